// Round 20
// baseline (119.998 us; speedup 1.0000x reference)
//
#include <hip/hip_runtime.h>
#include <hip/hip_bf16.h>
#include <math.h>

#define Mm 400
#define Cc 8
#define Ww 100
#define Dd 300
#define Hh 100
#define Rr 25
#define MC 3200   // M*C
#define KP 320    // K padded to multiple of 32
#define LBP_ITERS 5

typedef _Float16 f16x8 __attribute__((ext_vector_type(8)));
typedef _Float16 f16x4 __attribute__((ext_vector_type(4)));
typedef float f32x4 __attribute__((ext_vector_type(4)));

__device__ __forceinline__ void gload16(const void* g, void* l) {
  __builtin_amdgcn_global_load_lds(
      (const __attribute__((address_space(1))) void*)g,
      (__attribute__((address_space(3))) void*)l, 16, 0, 0);
}

// ---------------------------------------------------------------------------
// k_entity — r18 champion structure, ONE change: 1024 threads (16 waves)
// instead of 512 (8). Rationale: kernel is occupancy-starved (400 blocks =
// 1.56/CU; 29% occupancy); 16 waves halves u-phase serial depth (13->7 rows
// per wave) and doubles in-flight memory parallelism. Per-phase math is
// UNCHANGED (fixed-tid phases idle the extra waves at barriers).
// r19 lesson: no register hoists (compiler pins VGPR=48 and defeats them).
// ---------------------------------------------------------------------------
__global__ __launch_bounds__(1024) void k_entity(
    const float* __restrict__ ctxt_vec,   // [M][W][D]
    const float* __restrict__ cand_vec,   // [M][C][D]
    const float* __restrict__ A,          // [D]
    const float* __restrict__ B,          // [D]
    const float* __restrict__ Cl,         // [D]
    _Float16* __restrict__ Ah,            // [MC][KP]
    _Float16* __restrict__ Bh,            // [MC][KP]
    float* __restrict__ scores)           // [MC]
{
  const int m = blockIdx.x;
  const int tid = threadIdx.x;
  __shared__ __align__(16) float candA[Cc * 300];   // 9.6 KB
  __shared__ float u_s[Ww];
  __shared__ float beta_s[Ww];
  __shared__ int   idx_s[Ww];
  __shared__ int   cnt_s[2];
  __shared__ __align__(16) float cf_part[6 * 300];  // 7.2 KB
  __shared__ __align__(16) float cfB[304];

  const float* cev = cand_vec + (size_t)m * Cc * Dd;
  const float* cw  = ctxt_vec + (size_t)m * Ww * Dd;

  // ---- stage cand rows once: candA (LDS) + Ah/Bh (global fp16) ----
  for (int e = tid; e < 600; e += 1024) {           // 600 float4
    int c = e / 75, d4 = e - c * 75;
    float4 v = *(const float4*)(cev + c * Dd + d4 * 4);
    float4 a4 = *(const float4*)(A + d4 * 4);
    float4 c4 = *(const float4*)(Cl + d4 * 4);
    *(float4*)&candA[c * 300 + d4 * 4] =
        make_float4(v.x * a4.x, v.y * a4.y, v.z * a4.z, v.w * a4.w);
    size_t go = (size_t)(m * Cc + c) * KP + d4 * 4;
    f16x4 ah = { (_Float16)(v.x * c4.x), (_Float16)(v.y * c4.y),
                 (_Float16)(v.z * c4.z), (_Float16)(v.w * c4.w) };
    f16x4 bh = { (_Float16)v.x, (_Float16)v.y, (_Float16)v.z, (_Float16)v.w };
    *(f16x4*)(Ah + go) = ah;
    *(f16x4*)(Bh + go) = bh;
  }
  // zero k-pad k in [300,320) for this mention's 8 rows (8 rows x 5 f16x4)
  if (tid < 40) {
    int r = tid / 5, q = tid - r * 5;
    size_t go = (size_t)(m * Cc + r) * KP + 300 + q * 4;
    f16x4 z = {};
    *(f16x4*)(Ah + go) = z;
    *(f16x4*)(Bh + go) = z;
  }
  __syncthreads();

  // ---- u-phase: 16 waves, wave wv does w = wv, wv+16, ... (<=7 rows) ----
  {
    const int wv = tid >> 6, l = tid & 63;
    const int cg = l >> 3, d0 = l & 7;
    const float* ca = &candA[cg * 300];
    for (int w = wv; w < Ww; w += 16) {
      const float* row = cw + (size_t)w * Dd;
      float acc = 0.f;
#pragma unroll
      for (int k = 0; k < 10; ++k) {
        int d4 = d0 + k * 8;
        if (d4 < 75) {
          float4 x = *(const float4*)(row + d4 * 4);
          float4 e = *(const float4*)&ca[d4 * 4];
          acc += x.x * e.x + x.y * e.y + x.z * e.z + x.w * e.w;
        }
      }
      acc += __shfl_xor(acc, 1);
      acc += __shfl_xor(acc, 2);
      acc += __shfl_xor(acc, 4);               // group sum
      acc = fmaxf(acc, __shfl_xor(acc, 8));
      acc = fmaxf(acc, __shfl_xor(acc, 16));
      acc = fmaxf(acc, __shfl_xor(acc, 32));   // max over c
      if (l == 0) u_s[w] = acc;
    }
  }
  __syncthreads();

  // ---- topk (25th largest w/ multiplicity) + exact softmax, wave 0 ----
  if (tid < 64) {
    float a0 = u_s[tid];
    float a1 = (tid + 64 < Ww) ? u_s[tid + 64] : -1e30f;
    float q0 = a0, q1 = a1, sketch = 0.f;
    for (int r = 0; r < Rr; ++r) {
      float v; int idx;
      if (q1 > q0) { v = q1; idx = tid + 64; } else { v = q0; idx = tid; }
#pragma unroll
      for (int off = 1; off < 64; off <<= 1) {
        float ov = __shfl_xor(v, off);
        int   oi = __shfl_xor(idx, off);
        if (ov > v || (ov == v && oi < idx)) { v = ov; idx = oi; }
      }
      sketch = v;
      if (idx == tid) q0 = -1e30f;
      else if (idx == tid + 64) q1 = -1e30f;
    }
    float m0 = (a0 > sketch) ? a0 : sketch - 50.0f;
    float m1 = (tid + 64 < Ww) ? ((a1 > sketch) ? a1 : sketch - 50.0f) : -1e30f;
    float mx = fmaxf(m0, m1);
#pragma unroll
    for (int off = 1; off < 64; off <<= 1) mx = fmaxf(mx, __shfl_xor(mx, off));
    float e0 = expf(m0 - mx);
    float e1 = (tid + 64 < Ww) ? expf(m1 - mx) : 0.f;
    float s = e0 + e1;
#pragma unroll
    for (int off = 1; off < 64; off <<= 1) s += __shfl_xor(s, off);
    float inv = 1.0f / s;
    beta_s[tid] = e0 * inv;
    if (tid + 64 < Ww) beta_s[tid + 64] = e1 * inv;
  }
  __syncthreads();

  // ---- deterministic compaction: rows with beta > 1e-12 (waves 0,1) ----
  bool sel = false;
  unsigned long long bmask = 0;
  if (tid < 128) {
    sel = (tid < Ww) && (beta_s[tid] > 1e-12f);
    bmask = __ballot(sel);
    if ((tid & 63) == 0) cnt_s[tid >> 6] = (int)__popcll(bmask);
  }
  __syncthreads();
  if (tid < 128 && sel) {
    int lane = tid & 63;
    int base = (tid >> 6) ? cnt_s[0] : 0;
    int pos = base + (int)__popcll(bmask & ((1ull << lane) - 1ull));
    idx_s[pos] = tid;
  }
  __syncthreads();
  const int g = cnt_s[0] + cnt_s[1];

  // ---- gather-weighted ctxt_full: 6 groups x 75 d4-columns ----
  if (tid < 450) {
    int tg = tid / 75, d4 = tid - tg * 75;
    f32x4 cf = {};
    for (int i = tg; i < g; i += 6) {
      int w = idx_s[i];
      float4 x = *(const float4*)(cw + (size_t)w * Dd + d4 * 4);
      float bw = beta_s[w];
      cf[0] += bw * x.x; cf[1] += bw * x.y; cf[2] += bw * x.z; cf[3] += bw * x.w;
    }
    *(f32x4*)&cf_part[(tg * 75 + d4) * 4] = cf;
  }
  __syncthreads();

  if (tid < 75) {
    f32x4 s4 = *(const f32x4*)&cf_part[tid * 4];
#pragma unroll
    for (int tg = 1; tg < 6; ++tg) s4 += *(const f32x4*)&cf_part[(tg * 75 + tid) * 4];
    float4 b4 = *(const float4*)(B + tid * 4);
    s4[0] *= b4.x; s4[1] *= b4.y; s4[2] *= b4.z; s4[3] *= b4.w;
    *(f32x4*)&cfB[tid * 4] = s4;
  }
  __syncthreads();

  // ---- scores: 8 waves (tid < 512), one candidate per wave ----
  if (tid < 512) {
    int c = tid >> 6, lane = tid & 63;
    float p = 0.f;
    for (int d4 = lane; d4 < 75; d4 += 64) {
      float4 x = *(const float4*)(cev + (size_t)c * Dd + d4 * 4);
      f32x4 f = *(const f32x4*)&cfB[d4 * 4];
      p += x.x * f[0] + x.y * f[1] + x.z * f[2] + x.w * f[3];
    }
#pragma unroll
    for (int off = 32; off; off >>= 1) p += __shfl_down(p, off);
    if (lane == 0) scores[m * Cc + c] = p;
  }
}

// ---------------------------------------------------------------------------
// Kernel 2: P = Ah @ Bh^T  [3200 x 3200], K=320, fp16 MFMA, fp32 accum.
// 1D grid of 625 blocks with bijective XCD swizzle (T1/m204).
// ---------------------------------------------------------------------------
__global__ __launch_bounds__(256) void k_pairwise_mfma(
    const _Float16* __restrict__ Ah,  // [MC][KP]
    const _Float16* __restrict__ Bh,  // [MC][KP]
    _Float16* __restrict__ P)         // [MC][MC] fp16
{
  __shared__ __align__(16) _Float16 Sh[2][128 * 32];
  const int tid = threadIdx.x;
  const int wave = tid >> 6, lane = tid & 63;
  const int wr = wave >> 1, wc = wave & 1;

  // bijective XCD swizzle: nwg=625, q=78, r=1
  const int orig = blockIdx.x;
  const int xcd = orig & 7, idx = orig >> 3;
  const int qq = 625 / 8, rr = 625 % 8;
  const int wgid = (xcd < rr ? xcd * (qq + 1) : rr * (qq + 1) + (xcd - rr) * qq) + idx;
  const int bi = wgid / 25, bj = wgid - bi * 25;
  const int row0 = bi * 128, col0 = bj * 128;

  f32x4 acc[4][4] = {};
  const int fr = lane & 15, fq = lane >> 4;
  const int koff = fq * 8;

  for (int kt = 0; kt < KP / 32; ++kt) {
    const int k0 = kt * 32;
#pragma unroll
    for (int i = 0; i < 2; ++i) {
      int e = i * 256 + tid;
      int r = e >> 2;
      int kc = (e & 3) << 3;
      gload16(Ah + (size_t)(row0 + r) * KP + k0 + kc, (char*)Sh[0] + e * 16);
      gload16(Bh + (size_t)(col0 + r) * KP + k0 + kc, (char*)Sh[1] + e * 16);
    }
    __syncthreads();

    f16x8 af[4], bfr[4];
#pragma unroll
    for (int mi = 0; mi < 4; ++mi)
      af[mi] = *(const f16x8*)&Sh[0][(wr * 64 + mi * 16 + fr) * 32 + koff];
#pragma unroll
    for (int ni = 0; ni < 4; ++ni)
      bfr[ni] = *(const f16x8*)&Sh[1][(wc * 64 + ni * 16 + fr) * 32 + koff];
#pragma unroll
    for (int mi = 0; mi < 4; ++mi)
#pragma unroll
      for (int ni = 0; ni < 4; ++ni)
        acc[mi][ni] = __builtin_amdgcn_mfma_f32_16x16x32_f16(
            af[mi], bfr[ni], acc[mi][ni], 0, 0, 0);
    __syncthreads();
  }

  _Float16* wtile = (_Float16*)((char*)Sh + wave * 4096);
#pragma unroll
  for (int h = 0; h < 2; ++h) {
    __syncthreads();
#pragma unroll
    for (int mi2 = 0; mi2 < 2; ++mi2) {
      int mi = h * 2 + mi2;
#pragma unroll
      for (int ni = 0; ni < 4; ++ni)
#pragma unroll
        for (int r = 0; r < 4; ++r)
          wtile[(mi2 * 16 + fq * 4 + r) * 64 + ni * 16 + fr] =
              (_Float16)acc[mi][ni][r];
    }
    __syncthreads();
#pragma unroll
    for (int t = 0; t < 4; ++t) {
      int q = t * 64 + lane;
      int lr = q >> 3, lc8 = (q & 7) * 8;
      f16x8 v = *(const f16x8*)&wtile[lr * 64 + lc8];
      size_t gr = (size_t)(row0 + wr * 64 + h * 32 + lr);
      size_t gc = (size_t)(col0 + wc * 64 + lc8);
      *(f16x8*)(P + gr * MC + gc) = v;
    }
  }
}

// ---------------------------------------------------------------------------
// LBP step (proven config): exp-space, 4-way m-split, grid (Mm,4),
// 128 threads, col computed in registers. emsg fp16 [aa][m][8]
// (em >= 0.5^5 = 0.03125, fp16-safe).
// ---------------------------------------------------------------------------
__global__ __launch_bounds__(128) void k_lbp(
    const _Float16* __restrict__ P,
    const float* __restrict__ scores,
    const float* __restrict__ pIn,    // [4][MC] prev partials
    float* __restrict__ pOut,         // [4][MC]
    _Float16* __restrict__ emsg,      // [aa*400+m][8] fp16
    int first)
{
  const int aa = blockIdx.x, q = blockIdx.y;
  const int tid = threadIdx.x;
  __shared__ float red_s[2][Cc];

  float psum[Cc];
#pragma unroll
  for (int b = 0; b < Cc; ++b) psum[b] = 0.f;

  const int m = q * 100 + tid;
  if (tid < 100) {
    const int j8 = m * Cc;
    f32x4 s0 = *(const f32x4*)&scores[j8];
    f32x4 s1 = *(const f32x4*)&scores[j8 + 4];
    if (!first) {
#pragma unroll
      for (int p4 = 0; p4 < 4; ++p4) {
        s0 += *(const f32x4*)&pIn[p4 * MC + j8];
        s1 += *(const f32x4*)&pIn[p4 * MC + j8 + 4];
      }
    }
    float t[Cc];
#pragma unroll
    for (int b = 0; b < Cc; ++b) {
      f16x8 ph = *(const f16x8*)(P + (size_t)(aa * Cc + b) * MC + m * 8);
      float tb = fmaxf(fmaxf((float)ph[0] + s0[0], (float)ph[1] + s0[1]),
                       fmaxf((float)ph[2] + s0[2], (float)ph[3] + s0[3]));
      t[b] = fmaxf(tb, fmaxf(fmaxf((float)ph[4] + s1[0], (float)ph[5] + s1[1]),
                             fmaxf((float)ph[6] + s1[2], (float)ph[7] + s1[3])));
    }
    float mxt = t[0];
#pragma unroll
    for (int b = 1; b < Cc; ++b) mxt = fmaxf(mxt, t[b]);
    float se = 0.f;
#pragma unroll
    for (int b = 0; b < Cc; ++b) { float eb = expf(t[b] - mxt); t[b] = eb; se += eb; }
    float inv_se = 1.0f / se;
    bool self = (m == aa);

    _Float16* ep = emsg + ((size_t)aa * Mm + m) * Cc;
    f16x8 eo;
    if (!first) eo = *(const f16x8*)ep;
    f16x8 en;
#pragma unroll
    for (int b = 0; b < Cc; ++b) {
      float sel_e = self ? 1.0f : t[b] * inv_se;
      float old_e = first ? 1.0f : (float)eo[b];
      float nv = 0.5f * sel_e + 0.5f * old_e;
      en[b] = (_Float16)nv;
      psum[b] += logf(nv);
    }
    *(f16x8*)ep = en;
  }

  const int wave = tid >> 6, lane = tid & 63;
#pragma unroll
  for (int b = 0; b < Cc; ++b)
#pragma unroll
    for (int off = 32; off; off >>= 1) psum[b] += __shfl_down(psum[b], off);
  if (lane == 0)
#pragma unroll
    for (int b = 0; b < Cc; ++b) red_s[wave][b] = psum[b];
  __syncthreads();
  if (tid < Cc)
    pOut[q * MC + aa * Cc + tid] = red_s[0][tid] + red_s[1][tid];
}

// ---------------------------------------------------------------------------
// Final: colF = scores + sum_q p[q]; fgs = log_softmax(colF, axis=C); MLP.
// ---------------------------------------------------------------------------
__global__ __launch_bounds__(64) void k_final2(
    const float* __restrict__ scores,
    const float* __restrict__ pF,      // [4][MC]
    const float* __restrict__ pem,
    const float* __restrict__ W1,
    const float* __restrict__ b1,
    const float* __restrict__ W2,
    const float* __restrict__ b2,
    float* __restrict__ out)
{
  int m = blockIdx.x * 64 + threadIdx.x;
  if (m >= Mm) return;
  float f[Cc], pm[Cc];
#pragma unroll
  for (int c = 0; c < Cc; ++c) {
    int j = m * Cc + c;
    f[c] = scores[j] + pF[j] + pF[MC + j] + pF[2 * MC + j] + pF[3 * MC + j];
    pm[c] = pem[j];
  }
  float mx = f[0];
#pragma unroll
  for (int c = 1; c < Cc; ++c) mx = fmaxf(mx, f[c]);
  float se = 0.f;
#pragma unroll
  for (int c = 0; c < Cc; ++c) se += expf(f[c] - mx);
  float lse = mx + logf(se);
  float fgs[Cc], accv[Cc];
  float bb2 = b2[0];
#pragma unroll
  for (int c = 0; c < Cc; ++c) { fgs[c] = f[c] - lse; accv[c] = bb2; }
  for (int h = 0; h < Hh; ++h) {
    float w0 = W1[2 * h], w1 = W1[2 * h + 1], bb = b1[h], w2 = W2[h];
#pragma unroll
    for (int c = 0; c < Cc; ++c)
      accv[c] += w2 * fmaxf(fgs[c] * w0 + pm[c] * w1 + bb, 0.f);
  }
#pragma unroll
  for (int c = 0; c < Cc; ++c) out[m * Cc + c] = accv[c];
}

// ---------------------------------------------------------------------------
extern "C" void kernel_launch(void* const* d_in, const int* in_sizes, int n_in,
                              void* d_out, int out_size, void* d_ws, size_t ws_size,
                              hipStream_t stream) {
  const float* ctxt_vec = (const float*)d_in[1];   // [M][W][D]
  const float* cand_vec = (const float*)d_in[3];   // [M][C][D]
  const float* pem      = (const float*)d_in[4];   // [M][C]
  const float* A        = (const float*)d_in[5];
  const float* B        = (const float*)d_in[6];
  const float* Cl       = (const float*)d_in[7];
  const float* W1       = (const float*)d_in[8];
  const float* b1       = (const float*)d_in[9];
  const float* W2       = (const float*)d_in[10];
  const float* b2       = (const float*)d_in[11];
  float* out = (float*)d_out;

  char* ws = (char*)d_ws;
  _Float16* P     = (_Float16*)(ws);                      // 20,480,000 B
  _Float16* Ah    = (_Float16*)(ws + 20480000);           //  2,048,000 B
  _Float16* Bh    = (_Float16*)(ws + 20480000 + 2048000); //  2,048,000 B
  // emsg (fp16, 2,560,000 B) aliases Ah/Bh — both dead after the GEMM;
  // k_lbp (emsg writer) is stream-ordered after the GEMM.
  _Float16* emsg  = (_Float16*)(ws + 20480000);
  float*   scores = (float*)(ws + 25600000);              //     12,800 B
  float*   pp     = (float*)(ws + 25612800);              //    102,400 B [2][4][MC]

  k_entity<<<Mm, 1024, 0, stream>>>(ctxt_vec, cand_vec, A, B, Cl, Ah, Bh, scores);

  k_pairwise_mfma<<<625, 256, 0, stream>>>(Ah, Bh, P);

  // ping-pong partials: it0->pp0, it1->pp1, ..., it4->pp0
  float* pp0 = pp;
  float* pp1 = pp + 4 * MC;
  for (int it = 0; it < LBP_ITERS; ++it) {
    float* pout = (it & 1) ? pp1 : pp0;
    float* pin  = (it & 1) ? pp0 : pp1;
    k_lbp<<<dim3(Mm, 4), 128, 0, stream>>>(
        P, scores, pin, pout, emsg, it == 0 ? 1 : 0);
  }
  // last iter (it=4) wrote pp0
  k_final2<<<(Mm + 63) / 64, 64, 0, stream>>>(
      scores, pp0, pem, W1, b1, W2, b2, out);
}

// Round 21
// 119.431 us; speedup vs baseline: 1.0047x; 1.0047x over previous
//
#include <hip/hip_runtime.h>
#include <hip/hip_bf16.h>
#include <math.h>

#define Mm 400
#define Cc 8
#define Ww 100
#define Dd 300
#define Hh 100
#define Rr 25
#define MC 3200   // M*C
#define KP 320    // K padded to multiple of 32
#define LBP_ITERS 5

typedef _Float16 f16x8 __attribute__((ext_vector_type(8)));
typedef _Float16 f16x4 __attribute__((ext_vector_type(4)));
typedef float f32x4 __attribute__((ext_vector_type(4)));

__device__ __forceinline__ void gload16(const void* g, void* l) {
  __builtin_amdgcn_global_load_lds(
      (const __attribute__((address_space(1))) void*)g,
      (__attribute__((address_space(3))) void*)l, 16, 0, 0);
}

// ---------------------------------------------------------------------------
// k_entity (512 thr, one block per mention) — r18 champion + ONE u-phase
// change: COALESCED lane mapping. Old: lane=(cand,c-split d) -> every wave
// load was 8x-duplicated 128B (10 VMEM instr/row, ~128B unique each). New:
// lane l owns d4 in {l, 64+l} -> 2 fully-coalesced loads/row (1KB + 176B);
// each lane accumulates all 8 candidates from LDS; butterfly-reduce per c.
// Same FLOPs; sum order differs (~1e-6 rel on u). Ledger: occupancy edits
// (r19/r20) and phase splits (r15-r17) all regressed — only the VMEM
// instruction rate is still unaddressed.
// ---------------------------------------------------------------------------
__global__ __launch_bounds__(512) void k_entity(
    const float* __restrict__ ctxt_vec,   // [M][W][D]
    const float* __restrict__ cand_vec,   // [M][C][D]
    const float* __restrict__ A,          // [D]
    const float* __restrict__ B,          // [D]
    const float* __restrict__ Cl,         // [D]
    _Float16* __restrict__ Ah,            // [MC][KP]
    _Float16* __restrict__ Bh,            // [MC][KP]
    float* __restrict__ scores)           // [MC]
{
  const int m = blockIdx.x;
  const int tid = threadIdx.x;
  __shared__ __align__(16) float candA[Cc * 300];   // 9.6 KB
  __shared__ float u_s[Ww];
  __shared__ float beta_s[Ww];
  __shared__ int   idx_s[Ww];
  __shared__ int   cnt_s[2];
  __shared__ __align__(16) float cf_part[6 * 300];  // 7.2 KB
  __shared__ __align__(16) float cfB[304];

  const float* cev = cand_vec + (size_t)m * Cc * Dd;
  const float* cw  = ctxt_vec + (size_t)m * Ww * Dd;

  // ---- stage cand rows once: candA (LDS) + Ah/Bh (global fp16) ----
  for (int e = tid; e < 600; e += 512) {            // 600 float4
    int c = e / 75, d4 = e - c * 75;
    float4 v = *(const float4*)(cev + c * Dd + d4 * 4);
    float4 a4 = *(const float4*)(A + d4 * 4);
    float4 c4 = *(const float4*)(Cl + d4 * 4);
    *(float4*)&candA[c * 300 + d4 * 4] =
        make_float4(v.x * a4.x, v.y * a4.y, v.z * a4.z, v.w * a4.w);
    size_t go = (size_t)(m * Cc + c) * KP + d4 * 4;
    f16x4 ah = { (_Float16)(v.x * c4.x), (_Float16)(v.y * c4.y),
                 (_Float16)(v.z * c4.z), (_Float16)(v.w * c4.w) };
    f16x4 bh = { (_Float16)v.x, (_Float16)v.y, (_Float16)v.z, (_Float16)v.w };
    *(f16x4*)(Ah + go) = ah;
    *(f16x4*)(Bh + go) = bh;
  }
  // zero k-pad k in [300,320) for this mention's 8 rows (8 rows x 5 f16x4)
  if (tid < 40) {
    int r = tid / 5, q = tid - r * 5;
    size_t go = (size_t)(m * Cc + r) * KP + 300 + q * 4;
    f16x4 z = {};
    *(f16x4*)(Ah + go) = z;
    *(f16x4*)(Bh + go) = z;
  }
  __syncthreads();

  // ---- u-phase: 8 waves; wave wv does rows wv, wv+8, ...; lane l owns
  // d4 in {l, 64+l} (2 coalesced loads/row); all 8 candidates per lane ----
  {
    const int wv = tid >> 6, l = tid & 63;
    const bool hi = l < 11;                       // d4 = 64+l valid (<75)
    for (int w = wv; w < Ww; w += 8) {
      const float* row = cw + (size_t)w * Dd;
      f32x4 x0 = *(const f32x4*)(row + l * 4);
      f32x4 x1 = hi ? *(const f32x4*)(row + (64 + l) * 4)
                    : (f32x4){0.f, 0.f, 0.f, 0.f};
      float acc[Cc];
#pragma unroll
      for (int c = 0; c < Cc; ++c) {
        f32x4 e0 = *(const f32x4*)&candA[c * 300 + l * 4];
        float a = x0[0] * e0[0] + x0[1] * e0[1] + x0[2] * e0[2] + x0[3] * e0[3];
        if (hi) {
          f32x4 e1 = *(const f32x4*)&candA[c * 300 + (64 + l) * 4];
          a += x1[0] * e1[0] + x1[1] * e1[1] + x1[2] * e1[2] + x1[3] * e1[3];
        }
        acc[c] = a;
      }
#pragma unroll
      for (int c = 0; c < Cc; ++c)
#pragma unroll
        for (int off = 1; off < 64; off <<= 1)
          acc[c] += __shfl_xor(acc[c], off);
      float u = acc[0];
#pragma unroll
      for (int c = 1; c < Cc; ++c) u = fmaxf(u, acc[c]);
      if (l == 0) u_s[w] = u;
    }
  }
  __syncthreads();

  // ---- topk (25th largest w/ multiplicity) + exact softmax, wave 0 ----
  if (tid < 64) {
    float a0 = u_s[tid];
    float a1 = (tid + 64 < Ww) ? u_s[tid + 64] : -1e30f;
    float q0 = a0, q1 = a1, sketch = 0.f;
    for (int r = 0; r < Rr; ++r) {
      float v; int idx;
      if (q1 > q0) { v = q1; idx = tid + 64; } else { v = q0; idx = tid; }
#pragma unroll
      for (int off = 1; off < 64; off <<= 1) {
        float ov = __shfl_xor(v, off);
        int   oi = __shfl_xor(idx, off);
        if (ov > v || (ov == v && oi < idx)) { v = ov; idx = oi; }
      }
      sketch = v;
      if (idx == tid) q0 = -1e30f;
      else if (idx == tid + 64) q1 = -1e30f;
    }
    float m0 = (a0 > sketch) ? a0 : sketch - 50.0f;
    float m1 = (tid + 64 < Ww) ? ((a1 > sketch) ? a1 : sketch - 50.0f) : -1e30f;
    float mx = fmaxf(m0, m1);
#pragma unroll
    for (int off = 1; off < 64; off <<= 1) mx = fmaxf(mx, __shfl_xor(mx, off));
    float e0 = expf(m0 - mx);
    float e1 = (tid + 64 < Ww) ? expf(m1 - mx) : 0.f;
    float s = e0 + e1;
#pragma unroll
    for (int off = 1; off < 64; off <<= 1) s += __shfl_xor(s, off);
    float inv = 1.0f / s;
    beta_s[tid] = e0 * inv;
    if (tid + 64 < Ww) beta_s[tid + 64] = e1 * inv;
  }
  __syncthreads();

  // ---- deterministic compaction: rows with beta > 1e-12 (waves 0,1) ----
  bool sel = false;
  unsigned long long bmask = 0;
  if (tid < 128) {
    sel = (tid < Ww) && (beta_s[tid] > 1e-12f);
    bmask = __ballot(sel);
    if ((tid & 63) == 0) cnt_s[tid >> 6] = (int)__popcll(bmask);
  }
  __syncthreads();
  if (tid < 128 && sel) {
    int lane = tid & 63;
    int base = (tid >> 6) ? cnt_s[0] : 0;
    int pos = base + (int)__popcll(bmask & ((1ull << lane) - 1ull));
    idx_s[pos] = tid;
  }
  __syncthreads();
  const int g = cnt_s[0] + cnt_s[1];

  // ---- gather-weighted ctxt_full: 6 groups x 75 d4-columns ----
  if (tid < 450) {
    int tg = tid / 75, d4 = tid - tg * 75;
    f32x4 cf = {};
    for (int i = tg; i < g; i += 6) {
      int w = idx_s[i];
      float4 x = *(const float4*)(cw + (size_t)w * Dd + d4 * 4);
      float bw = beta_s[w];
      cf[0] += bw * x.x; cf[1] += bw * x.y; cf[2] += bw * x.z; cf[3] += bw * x.w;
    }
    *(f32x4*)&cf_part[(tg * 75 + d4) * 4] = cf;
  }
  __syncthreads();

  if (tid < 75) {
    f32x4 s4 = *(const f32x4*)&cf_part[tid * 4];
#pragma unroll
    for (int tg = 1; tg < 6; ++tg) s4 += *(const f32x4*)&cf_part[(tg * 75 + tid) * 4];
    float4 b4 = *(const float4*)(B + tid * 4);
    s4[0] *= b4.x; s4[1] *= b4.y; s4[2] *= b4.z; s4[3] *= b4.w;
    *(f32x4*)&cfB[tid * 4] = s4;
  }
  __syncthreads();

  // ---- scores: 8 waves, one candidate per wave ----
  {
    int c = tid >> 6, lane = tid & 63;
    float p = 0.f;
    for (int d4 = lane; d4 < 75; d4 += 64) {
      float4 x = *(const float4*)(cev + (size_t)c * Dd + d4 * 4);
      f32x4 f = *(const f32x4*)&cfB[d4 * 4];
      p += x.x * f[0] + x.y * f[1] + x.z * f[2] + x.w * f[3];
    }
#pragma unroll
    for (int off = 32; off; off >>= 1) p += __shfl_down(p, off);
    if (lane == 0) scores[m * Cc + c] = p;
  }
}

// ---------------------------------------------------------------------------
// Kernel 2: P = Ah @ Bh^T  [3200 x 3200], K=320, fp16 MFMA, fp32 accum.
// 1D grid of 625 blocks with bijective XCD swizzle (T1/m204).
// ---------------------------------------------------------------------------
__global__ __launch_bounds__(256) void k_pairwise_mfma(
    const _Float16* __restrict__ Ah,  // [MC][KP]
    const _Float16* __restrict__ Bh,  // [MC][KP]
    _Float16* __restrict__ P)         // [MC][MC] fp16
{
  __shared__ __align__(16) _Float16 Sh[2][128 * 32];
  const int tid = threadIdx.x;
  const int wave = tid >> 6, lane = tid & 63;
  const int wr = wave >> 1, wc = wave & 1;

  // bijective XCD swizzle: nwg=625, q=78, r=1
  const int orig = blockIdx.x;
  const int xcd = orig & 7, idx = orig >> 3;
  const int qq = 625 / 8, rr = 625 % 8;
  const int wgid = (xcd < rr ? xcd * (qq + 1) : rr * (qq + 1) + (xcd - rr) * qq) + idx;
  const int bi = wgid / 25, bj = wgid - bi * 25;
  const int row0 = bi * 128, col0 = bj * 128;

  f32x4 acc[4][4] = {};
  const int fr = lane & 15, fq = lane >> 4;
  const int koff = fq * 8;

  for (int kt = 0; kt < KP / 32; ++kt) {
    const int k0 = kt * 32;
#pragma unroll
    for (int i = 0; i < 2; ++i) {
      int e = i * 256 + tid;
      int r = e >> 2;
      int kc = (e & 3) << 3;
      gload16(Ah + (size_t)(row0 + r) * KP + k0 + kc, (char*)Sh[0] + e * 16);
      gload16(Bh + (size_t)(col0 + r) * KP + k0 + kc, (char*)Sh[1] + e * 16);
    }
    __syncthreads();

    f16x8 af[4], bfr[4];
#pragma unroll
    for (int mi = 0; mi < 4; ++mi)
      af[mi] = *(const f16x8*)&Sh[0][(wr * 64 + mi * 16 + fr) * 32 + koff];
#pragma unroll
    for (int ni = 0; ni < 4; ++ni)
      bfr[ni] = *(const f16x8*)&Sh[1][(wc * 64 + ni * 16 + fr) * 32 + koff];
#pragma unroll
    for (int mi = 0; mi < 4; ++mi)
#pragma unroll
      for (int ni = 0; ni < 4; ++ni)
        acc[mi][ni] = __builtin_amdgcn_mfma_f32_16x16x32_f16(
            af[mi], bfr[ni], acc[mi][ni], 0, 0, 0);
    __syncthreads();
  }

  _Float16* wtile = (_Float16*)((char*)Sh + wave * 4096);
#pragma unroll
  for (int h = 0; h < 2; ++h) {
    __syncthreads();
#pragma unroll
    for (int mi2 = 0; mi2 < 2; ++mi2) {
      int mi = h * 2 + mi2;
#pragma unroll
      for (int ni = 0; ni < 4; ++ni)
#pragma unroll
        for (int r = 0; r < 4; ++r)
          wtile[(mi2 * 16 + fq * 4 + r) * 64 + ni * 16 + fr] =
              (_Float16)acc[mi][ni][r];
    }
    __syncthreads();
#pragma unroll
    for (int t = 0; t < 4; ++t) {
      int q = t * 64 + lane;
      int lr = q >> 3, lc8 = (q & 7) * 8;
      f16x8 v = *(const f16x8*)&wtile[lr * 64 + lc8];
      size_t gr = (size_t)(row0 + wr * 64 + h * 32 + lr);
      size_t gc = (size_t)(col0 + wc * 64 + lc8);
      *(f16x8*)(P + gr * MC + gc) = v;
    }
  }
}

// ---------------------------------------------------------------------------
// LBP step (proven config): exp-space, 4-way m-split, grid (Mm,4),
// 128 threads, col computed in registers. emsg fp16 [aa][m][8]
// (em >= 0.5^5 = 0.03125, fp16-safe).
// ---------------------------------------------------------------------------
__global__ __launch_bounds__(128) void k_lbp(
    const _Float16* __restrict__ P,
    const float* __restrict__ scores,
    const float* __restrict__ pIn,    // [4][MC] prev partials
    float* __restrict__ pOut,         // [4][MC]
    _Float16* __restrict__ emsg,      // [aa*400+m][8] fp16
    int first)
{
  const int aa = blockIdx.x, q = blockIdx.y;
  const int tid = threadIdx.x;
  __shared__ float red_s[2][Cc];

  float psum[Cc];
#pragma unroll
  for (int b = 0; b < Cc; ++b) psum[b] = 0.f;

  const int m = q * 100 + tid;
  if (tid < 100) {
    const int j8 = m * Cc;
    f32x4 s0 = *(const f32x4*)&scores[j8];
    f32x4 s1 = *(const f32x4*)&scores[j8 + 4];
    if (!first) {
#pragma unroll
      for (int p4 = 0; p4 < 4; ++p4) {
        s0 += *(const f32x4*)&pIn[p4 * MC + j8];
        s1 += *(const f32x4*)&pIn[p4 * MC + j8 + 4];
      }
    }
    float t[Cc];
#pragma unroll
    for (int b = 0; b < Cc; ++b) {
      f16x8 ph = *(const f16x8*)(P + (size_t)(aa * Cc + b) * MC + m * 8);
      float tb = fmaxf(fmaxf((float)ph[0] + s0[0], (float)ph[1] + s0[1]),
                       fmaxf((float)ph[2] + s0[2], (float)ph[3] + s0[3]));
      t[b] = fmaxf(tb, fmaxf(fmaxf((float)ph[4] + s1[0], (float)ph[5] + s1[1]),
                             fmaxf((float)ph[6] + s1[2], (float)ph[7] + s1[3])));
    }
    float mxt = t[0];
#pragma unroll
    for (int b = 1; b < Cc; ++b) mxt = fmaxf(mxt, t[b]);
    float se = 0.f;
#pragma unroll
    for (int b = 0; b < Cc; ++b) { float eb = expf(t[b] - mxt); t[b] = eb; se += eb; }
    float inv_se = 1.0f / se;
    bool self = (m == aa);

    _Float16* ep = emsg + ((size_t)aa * Mm + m) * Cc;
    f16x8 eo;
    if (!first) eo = *(const f16x8*)ep;
    f16x8 en;
#pragma unroll
    for (int b = 0; b < Cc; ++b) {
      float sel_e = self ? 1.0f : t[b] * inv_se;
      float old_e = first ? 1.0f : (float)eo[b];
      float nv = 0.5f * sel_e + 0.5f * old_e;
      en[b] = (_Float16)nv;
      psum[b] += logf(nv);
    }
    *(f16x8*)ep = en;
  }

  const int wave = tid >> 6, lane = tid & 63;
#pragma unroll
  for (int b = 0; b < Cc; ++b)
#pragma unroll
    for (int off = 32; off; off >>= 1) psum[b] += __shfl_down(psum[b], off);
  if (lane == 0)
#pragma unroll
    for (int b = 0; b < Cc; ++b) red_s[wave][b] = psum[b];
  __syncthreads();
  if (tid < Cc)
    pOut[q * MC + aa * Cc + tid] = red_s[0][tid] + red_s[1][tid];
}

// ---------------------------------------------------------------------------
// Final: colF = scores + sum_q p[q]; fgs = log_softmax(colF, axis=C); MLP.
// ---------------------------------------------------------------------------
__global__ __launch_bounds__(64) void k_final2(
    const float* __restrict__ scores,
    const float* __restrict__ pF,      // [4][MC]
    const float* __restrict__ pem,
    const float* __restrict__ W1,
    const float* __restrict__ b1,
    const float* __restrict__ W2,
    const float* __restrict__ b2,
    float* __restrict__ out)
{
  int m = blockIdx.x * 64 + threadIdx.x;
  if (m >= Mm) return;
  float f[Cc], pm[Cc];
#pragma unroll
  for (int c = 0; c < Cc; ++c) {
    int j = m * Cc + c;
    f[c] = scores[j] + pF[j] + pF[MC + j] + pF[2 * MC + j] + pF[3 * MC + j];
    pm[c] = pem[j];
  }
  float mx = f[0];
#pragma unroll
  for (int c = 1; c < Cc; ++c) mx = fmaxf(mx, f[c]);
  float se = 0.f;
#pragma unroll
  for (int c = 0; c < Cc; ++c) se += expf(f[c] - mx);
  float lse = mx + logf(se);
  float fgs[Cc], accv[Cc];
  float bb2 = b2[0];
#pragma unroll
  for (int c = 0; c < Cc; ++c) { fgs[c] = f[c] - lse; accv[c] = bb2; }
  for (int h = 0; h < Hh; ++h) {
    float w0 = W1[2 * h], w1 = W1[2 * h + 1], bb = b1[h], w2 = W2[h];
#pragma unroll
    for (int c = 0; c < Cc; ++c)
      accv[c] += w2 * fmaxf(fgs[c] * w0 + pm[c] * w1 + bb, 0.f);
  }
#pragma unroll
  for (int c = 0; c < Cc; ++c) out[m * Cc + c] = accv[c];
}

// ---------------------------------------------------------------------------
extern "C" void kernel_launch(void* const* d_in, const int* in_sizes, int n_in,
                              void* d_out, int out_size, void* d_ws, size_t ws_size,
                              hipStream_t stream) {
  const float* ctxt_vec = (const float*)d_in[1];   // [M][W][D]
  const float* cand_vec = (const float*)d_in[3];   // [M][C][D]
  const float* pem      = (const float*)d_in[4];   // [M][C]
  const float* A        = (const float*)d_in[5];
  const float* B        = (const float*)d_in[6];
  const float* Cl       = (const float*)d_in[7];
  const float* W1       = (const float*)d_in[8];
  const float* b1       = (const float*)d_in[9];
  const float* W2       = (const float*)d_in[10];
  const float* b2       = (const float*)d_in[11];
  float* out = (float*)d_out;

  char* ws = (char*)d_ws;
  _Float16* P     = (_Float16*)(ws);                      // 20,480,000 B
  _Float16* Ah    = (_Float16*)(ws + 20480000);           //  2,048,000 B
  _Float16* Bh    = (_Float16*)(ws + 20480000 + 2048000); //  2,048,000 B
  // emsg (fp16, 2,560,000 B) aliases Ah/Bh — both dead after the GEMM;
  // k_lbp (emsg writer) is stream-ordered after the GEMM.
  _Float16* emsg  = (_Float16*)(ws + 20480000);
  float*   scores = (float*)(ws + 25600000);              //     12,800 B
  float*   pp     = (float*)(ws + 25612800);              //    102,400 B [2][4][MC]

  k_entity<<<Mm, 512, 0, stream>>>(ctxt_vec, cand_vec, A, B, Cl, Ah, Bh, scores);

  k_pairwise_mfma<<<625, 256, 0, stream>>>(Ah, Bh, P);

  // ping-pong partials: it0->pp0, it1->pp1, ..., it4->pp0
  float* pp0 = pp;
  float* pp1 = pp + 4 * MC;
  for (int it = 0; it < LBP_ITERS; ++it) {
    float* pout = (it & 1) ? pp1 : pp0;
    float* pin  = (it & 1) ? pp0 : pp1;
    k_lbp<<<dim3(Mm, 4), 128, 0, stream>>>(
        P, scores, pin, pout, emsg, it == 0 ? 1 : 0);
  }
  // last iter (it=4) wrote pp0
  k_final2<<<(Mm + 63) / 64, 64, 0, stream>>>(
      scores, pp0, pem, W1, b1, W2, b2, out);
}

// Round 22
// 92.750 us; speedup vs baseline: 1.2938x; 1.2877x over previous
//
#include <hip/hip_runtime.h>
#include <hip/hip_bf16.h>
#include <math.h>

#define Mm 400
#define Cc 8
#define Ww 100
#define Dd 300
#define Hh 100
#define Rr 25
#define MC 3200   // M*C
#define KP 320    // K padded to multiple of 32
#define LBP_ITERS 5

typedef _Float16 f16x8 __attribute__((ext_vector_type(8)));
typedef _Float16 f16x4 __attribute__((ext_vector_type(4)));
typedef float f32x4 __attribute__((ext_vector_type(4)));

__device__ __forceinline__ void gload16(const void* g, void* l) {
  __builtin_amdgcn_global_load_lds(
      (const __attribute__((address_space(1))) void*)g,
      (__attribute__((address_space(3))) void*)l, 16, 0, 0);
}

// ---------------------------------------------------------------------------
// k_entity (512 thr, one block per mention) — r18 champion + ONE change:
// topk via EXACT RADIX-SELECT on flipped float bits (32 x {ballot,popc},
// ~1K cycles) instead of 25 rounds x 6-deep shfl butterfly (~18K dependent
// LDS-pipe cycles on wave 0 while 7 waves idle). Same value, deterministic:
// V = max{t : count(flip >= t) >= 25} = 25th-largest with multiplicity.
// Evidence: warm LLC-resident replays run at the SAME ~50us as cold ->
// latency-bound, shfl chains are the serial cost (m117: ~120cyc dependent).
// ---------------------------------------------------------------------------
__global__ __launch_bounds__(512) void k_entity(
    const float* __restrict__ ctxt_vec,   // [M][W][D]
    const float* __restrict__ cand_vec,   // [M][C][D]
    const float* __restrict__ A,          // [D]
    const float* __restrict__ B,          // [D]
    const float* __restrict__ Cl,         // [D]
    _Float16* __restrict__ Ah,            // [MC][KP]
    _Float16* __restrict__ Bh,            // [MC][KP]
    float* __restrict__ scores)           // [MC]
{
  const int m = blockIdx.x;
  const int tid = threadIdx.x;
  __shared__ __align__(16) float candA[Cc * 300];   // 9.6 KB
  __shared__ float u_s[Ww];
  __shared__ float beta_s[Ww];
  __shared__ int   idx_s[Ww];
  __shared__ int   cnt_s[2];
  __shared__ __align__(16) float cf_part[6 * 300];  // 7.2 KB
  __shared__ __align__(16) float cfB[304];

  const float* cev = cand_vec + (size_t)m * Cc * Dd;
  const float* cw  = ctxt_vec + (size_t)m * Ww * Dd;

  // ---- stage cand rows once: candA (LDS) + Ah/Bh (global fp16) ----
  for (int e = tid; e < 600; e += 512) {            // 600 float4
    int c = e / 75, d4 = e - c * 75;
    float4 v = *(const float4*)(cev + c * Dd + d4 * 4);
    float4 a4 = *(const float4*)(A + d4 * 4);
    float4 c4 = *(const float4*)(Cl + d4 * 4);
    *(float4*)&candA[c * 300 + d4 * 4] =
        make_float4(v.x * a4.x, v.y * a4.y, v.z * a4.z, v.w * a4.w);
    size_t go = (size_t)(m * Cc + c) * KP + d4 * 4;
    f16x4 ah = { (_Float16)(v.x * c4.x), (_Float16)(v.y * c4.y),
                 (_Float16)(v.z * c4.z), (_Float16)(v.w * c4.w) };
    f16x4 bh = { (_Float16)v.x, (_Float16)v.y, (_Float16)v.z, (_Float16)v.w };
    *(f16x4*)(Ah + go) = ah;
    *(f16x4*)(Bh + go) = bh;
  }
  // zero k-pad k in [300,320) for this mention's 8 rows (8 rows x 5 f16x4)
  if (tid < 40) {
    int r = tid / 5, q = tid - r * 5;
    size_t go = (size_t)(m * Cc + r) * KP + 300 + q * 4;
    f16x4 z = {};
    *(f16x4*)(Ah + go) = z;
    *(f16x4*)(Bh + go) = z;
  }
  __syncthreads();

  // ---- u-phase: 8 waves, wave wv does w = wv, wv+8, ... (r18 mapping) ----
  {
    const int wv = tid >> 6, l = tid & 63;
    const int cg = l >> 3, d0 = l & 7;
    const float* ca = &candA[cg * 300];
    for (int w = wv; w < Ww; w += 8) {
      const float* row = cw + (size_t)w * Dd;
      float acc = 0.f;
#pragma unroll
      for (int k = 0; k < 10; ++k) {
        int d4 = d0 + k * 8;
        if (d4 < 75) {
          float4 x = *(const float4*)(row + d4 * 4);
          float4 e = *(const float4*)&ca[d4 * 4];
          acc += x.x * e.x + x.y * e.y + x.z * e.z + x.w * e.w;
        }
      }
      acc += __shfl_xor(acc, 1);
      acc += __shfl_xor(acc, 2);
      acc += __shfl_xor(acc, 4);               // group sum
      acc = fmaxf(acc, __shfl_xor(acc, 8));
      acc = fmaxf(acc, __shfl_xor(acc, 16));
      acc = fmaxf(acc, __shfl_xor(acc, 32));   // max over c
      if (l == 0) u_s[w] = acc;
    }
  }
  __syncthreads();

  // ---- topk: EXACT radix-select of 25th largest (w/ multiplicity) ----
  if (tid < 64) {
    float a0 = u_s[tid];
    const bool v1 = (tid + 64 < Ww);
    float a1 = v1 ? u_s[tid + 64] : -1e30f;
    // order-preserving flip: negative -> ~bits, non-negative -> bits | MSB
    unsigned int u0 = __float_as_uint(a0);
    u0 = (u0 & 0x80000000u) ? ~u0 : (u0 | 0x80000000u);
    unsigned int u1 = 0;
    if (v1) {
      unsigned int t = __float_as_uint(a1);
      u1 = (t & 0x80000000u) ? ~t : (t | 0x80000000u);
    }
    unsigned int V = 0;
#pragma unroll
    for (int bit = 31; bit >= 0; --bit) {
      unsigned int trial = V | (1u << bit);
      unsigned long long b0 = __ballot(u0 >= trial);
      unsigned long long b1 = __ballot(v1 && (u1 >= trial));
      if (__popcll(b0) + __popcll(b1) >= Rr) V = trial;
    }
    unsigned int sb = (V & 0x80000000u) ? (V & 0x7fffffffu) : ~V;
    float sketch = __uint_as_float(sb);

    // Threshold(0,-50) + exact softmax over the 100 u values
    float m0 = (a0 > sketch) ? a0 : sketch - 50.0f;
    float m1 = v1 ? ((a1 > sketch) ? a1 : sketch - 50.0f) : -1e30f;
    float mx = fmaxf(m0, m1);
#pragma unroll
    for (int off = 1; off < 64; off <<= 1) mx = fmaxf(mx, __shfl_xor(mx, off));
    float e0 = expf(m0 - mx);
    float e1 = v1 ? expf(m1 - mx) : 0.f;
    float s = e0 + e1;
#pragma unroll
    for (int off = 1; off < 64; off <<= 1) s += __shfl_xor(s, off);
    float inv = 1.0f / s;
    beta_s[tid] = e0 * inv;
    if (v1) beta_s[tid + 64] = e1 * inv;
  }
  __syncthreads();

  // ---- deterministic compaction: rows with beta > 1e-12 (waves 0,1) ----
  bool sel = false;
  unsigned long long bmask = 0;
  if (tid < 128) {
    sel = (tid < Ww) && (beta_s[tid] > 1e-12f);
    bmask = __ballot(sel);
    if ((tid & 63) == 0) cnt_s[tid >> 6] = (int)__popcll(bmask);
  }
  __syncthreads();
  if (tid < 128 && sel) {
    int lane = tid & 63;
    int base = (tid >> 6) ? cnt_s[0] : 0;
    int pos = base + (int)__popcll(bmask & ((1ull << lane) - 1ull));
    idx_s[pos] = tid;
  }
  __syncthreads();
  const int g = cnt_s[0] + cnt_s[1];

  // ---- gather-weighted ctxt_full: 6 groups x 75 d4-columns ----
  if (tid < 450) {
    int tg = tid / 75, d4 = tid - tg * 75;
    f32x4 cf = {};
    for (int i = tg; i < g; i += 6) {
      int w = idx_s[i];
      float4 x = *(const float4*)(cw + (size_t)w * Dd + d4 * 4);
      float bw = beta_s[w];
      cf[0] += bw * x.x; cf[1] += bw * x.y; cf[2] += bw * x.z; cf[3] += bw * x.w;
    }
    *(f32x4*)&cf_part[(tg * 75 + d4) * 4] = cf;
  }
  __syncthreads();

  if (tid < 75) {
    f32x4 s4 = *(const f32x4*)&cf_part[tid * 4];
#pragma unroll
    for (int tg = 1; tg < 6; ++tg) s4 += *(const f32x4*)&cf_part[(tg * 75 + tid) * 4];
    float4 b4 = *(const float4*)(B + tid * 4);
    s4[0] *= b4.x; s4[1] *= b4.y; s4[2] *= b4.z; s4[3] *= b4.w;
    *(f32x4*)&cfB[tid * 4] = s4;
  }
  __syncthreads();

  // ---- scores: 8 waves, one candidate per wave ----
  {
    int c = tid >> 6, lane = tid & 63;
    float p = 0.f;
    for (int d4 = lane; d4 < 75; d4 += 64) {
      float4 x = *(const float4*)(cev + (size_t)c * Dd + d4 * 4);
      f32x4 f = *(const f32x4*)&cfB[d4 * 4];
      p += x.x * f[0] + x.y * f[1] + x.z * f[2] + x.w * f[3];
    }
#pragma unroll
    for (int off = 32; off; off >>= 1) p += __shfl_down(p, off);
    if (lane == 0) scores[m * Cc + c] = p;
  }
}

// ---------------------------------------------------------------------------
// Kernel 2: P = Ah @ Bh^T  [3200 x 3200], K=320, fp16 MFMA, fp32 accum.
// 1D grid of 625 blocks with bijective XCD swizzle (T1/m204).
// ---------------------------------------------------------------------------
__global__ __launch_bounds__(256) void k_pairwise_mfma(
    const _Float16* __restrict__ Ah,  // [MC][KP]
    const _Float16* __restrict__ Bh,  // [MC][KP]
    _Float16* __restrict__ P)         // [MC][MC] fp16
{
  __shared__ __align__(16) _Float16 Sh[2][128 * 32];
  const int tid = threadIdx.x;
  const int wave = tid >> 6, lane = tid & 63;
  const int wr = wave >> 1, wc = wave & 1;

  // bijective XCD swizzle: nwg=625, q=78, r=1
  const int orig = blockIdx.x;
  const int xcd = orig & 7, idx = orig >> 3;
  const int qq = 625 / 8, rr = 625 % 8;
  const int wgid = (xcd < rr ? xcd * (qq + 1) : rr * (qq + 1) + (xcd - rr) * qq) + idx;
  const int bi = wgid / 25, bj = wgid - bi * 25;
  const int row0 = bi * 128, col0 = bj * 128;

  f32x4 acc[4][4] = {};
  const int fr = lane & 15, fq = lane >> 4;
  const int koff = fq * 8;

  for (int kt = 0; kt < KP / 32; ++kt) {
    const int k0 = kt * 32;
#pragma unroll
    for (int i = 0; i < 2; ++i) {
      int e = i * 256 + tid;
      int r = e >> 2;
      int kc = (e & 3) << 3;
      gload16(Ah + (size_t)(row0 + r) * KP + k0 + kc, (char*)Sh[0] + e * 16);
      gload16(Bh + (size_t)(col0 + r) * KP + k0 + kc, (char*)Sh[1] + e * 16);
    }
    __syncthreads();

    f16x8 af[4], bfr[4];
#pragma unroll
    for (int mi = 0; mi < 4; ++mi)
      af[mi] = *(const f16x8*)&Sh[0][(wr * 64 + mi * 16 + fr) * 32 + koff];
#pragma unroll
    for (int ni = 0; ni < 4; ++ni)
      bfr[ni] = *(const f16x8*)&Sh[1][(wc * 64 + ni * 16 + fr) * 32 + koff];
#pragma unroll
    for (int mi = 0; mi < 4; ++mi)
#pragma unroll
      for (int ni = 0; ni < 4; ++ni)
        acc[mi][ni] = __builtin_amdgcn_mfma_f32_16x16x32_f16(
            af[mi], bfr[ni], acc[mi][ni], 0, 0, 0);
    __syncthreads();
  }

  _Float16* wtile = (_Float16*)((char*)Sh + wave * 4096);
#pragma unroll
  for (int h = 0; h < 2; ++h) {
    __syncthreads();
#pragma unroll
    for (int mi2 = 0; mi2 < 2; ++mi2) {
      int mi = h * 2 + mi2;
#pragma unroll
      for (int ni = 0; ni < 4; ++ni)
#pragma unroll
        for (int r = 0; r < 4; ++r)
          wtile[(mi2 * 16 + fq * 4 + r) * 64 + ni * 16 + fr] =
              (_Float16)acc[mi][ni][r];
    }
    __syncthreads();
#pragma unroll
    for (int t = 0; t < 4; ++t) {
      int q = t * 64 + lane;
      int lr = q >> 3, lc8 = (q & 7) * 8;
      f16x8 v = *(const f16x8*)&wtile[lr * 64 + lc8];
      size_t gr = (size_t)(row0 + wr * 64 + h * 32 + lr);
      size_t gc = (size_t)(col0 + wc * 64 + lc8);
      *(f16x8*)(P + gr * MC + gc) = v;
    }
  }
}

// ---------------------------------------------------------------------------
// LBP step (proven config): exp-space, 4-way m-split, grid (Mm,4),
// 128 threads, col computed in registers. emsg fp16 [aa][m][8]
// (em >= 0.5^5 = 0.03125, fp16-safe).
// ---------------------------------------------------------------------------
__global__ __launch_bounds__(128) void k_lbp(
    const _Float16* __restrict__ P,
    const float* __restrict__ scores,
    const float* __restrict__ pIn,    // [4][MC] prev partials
    float* __restrict__ pOut,         // [4][MC]
    _Float16* __restrict__ emsg,      // [aa*400+m][8] fp16
    int first)
{
  const int aa = blockIdx.x, q = blockIdx.y;
  const int tid = threadIdx.x;
  __shared__ float red_s[2][Cc];

  float psum[Cc];
#pragma unroll
  for (int b = 0; b < Cc; ++b) psum[b] = 0.f;

  const int m = q * 100 + tid;
  if (tid < 100) {
    const int j8 = m * Cc;
    f32x4 s0 = *(const f32x4*)&scores[j8];
    f32x4 s1 = *(const f32x4*)&scores[j8 + 4];
    if (!first) {
#pragma unroll
      for (int p4 = 0; p4 < 4; ++p4) {
        s0 += *(const f32x4*)&pIn[p4 * MC + j8];
        s1 += *(const f32x4*)&pIn[p4 * MC + j8 + 4];
      }
    }
    float t[Cc];
#pragma unroll
    for (int b = 0; b < Cc; ++b) {
      f16x8 ph = *(const f16x8*)(P + (size_t)(aa * Cc + b) * MC + m * 8);
      float tb = fmaxf(fmaxf((float)ph[0] + s0[0], (float)ph[1] + s0[1]),
                       fmaxf((float)ph[2] + s0[2], (float)ph[3] + s0[3]));
      t[b] = fmaxf(tb, fmaxf(fmaxf((float)ph[4] + s1[0], (float)ph[5] + s1[1]),
                             fmaxf((float)ph[6] + s1[2], (float)ph[7] + s1[3])));
    }
    float mxt = t[0];
#pragma unroll
    for (int b = 1; b < Cc; ++b) mxt = fmaxf(mxt, t[b]);
    float se = 0.f;
#pragma unroll
    for (int b = 0; b < Cc; ++b) { float eb = expf(t[b] - mxt); t[b] = eb; se += eb; }
    float inv_se = 1.0f / se;
    bool self = (m == aa);

    _Float16* ep = emsg + ((size_t)aa * Mm + m) * Cc;
    f16x8 eo;
    if (!first) eo = *(const f16x8*)ep;
    f16x8 en;
#pragma unroll
    for (int b = 0; b < Cc; ++b) {
      float sel_e = self ? 1.0f : t[b] * inv_se;
      float old_e = first ? 1.0f : (float)eo[b];
      float nv = 0.5f * sel_e + 0.5f * old_e;
      en[b] = (_Float16)nv;
      psum[b] += logf(nv);
    }
    *(f16x8*)ep = en;
  }

  const int wave = tid >> 6, lane = tid & 63;
#pragma unroll
  for (int b = 0; b < Cc; ++b)
#pragma unroll
    for (int off = 32; off; off >>= 1) psum[b] += __shfl_down(psum[b], off);
  if (lane == 0)
#pragma unroll
    for (int b = 0; b < Cc; ++b) red_s[wave][b] = psum[b];
  __syncthreads();
  if (tid < Cc)
    pOut[q * MC + aa * Cc + tid] = red_s[0][tid] + red_s[1][tid];
}

// ---------------------------------------------------------------------------
// Final: colF = scores + sum_q p[q]; fgs = log_softmax(colF, axis=C); MLP.
// ---------------------------------------------------------------------------
__global__ __launch_bounds__(64) void k_final2(
    const float* __restrict__ scores,
    const float* __restrict__ pF,      // [4][MC]
    const float* __restrict__ pem,
    const float* __restrict__ W1,
    const float* __restrict__ b1,
    const float* __restrict__ W2,
    const float* __restrict__ b2,
    float* __restrict__ out)
{
  int m = blockIdx.x * 64 + threadIdx.x;
  if (m >= Mm) return;
  float f[Cc], pm[Cc];
#pragma unroll
  for (int c = 0; c < Cc; ++c) {
    int j = m * Cc + c;
    f[c] = scores[j] + pF[j] + pF[MC + j] + pF[2 * MC + j] + pF[3 * MC + j];
    pm[c] = pem[j];
  }
  float mx = f[0];
#pragma unroll
  for (int c = 1; c < Cc; ++c) mx = fmaxf(mx, f[c]);
  float se = 0.f;
#pragma unroll
  for (int c = 0; c < Cc; ++c) se += expf(f[c] - mx);
  float lse = mx + logf(se);
  float fgs[Cc], accv[Cc];
  float bb2 = b2[0];
#pragma unroll
  for (int c = 0; c < Cc; ++c) { fgs[c] = f[c] - lse; accv[c] = bb2; }
  for (int h = 0; h < Hh; ++h) {
    float w0 = W1[2 * h], w1 = W1[2 * h + 1], bb = b1[h], w2 = W2[h];
#pragma unroll
    for (int c = 0; c < Cc; ++c)
      accv[c] += w2 * fmaxf(fgs[c] * w0 + pm[c] * w1 + bb, 0.f);
  }
#pragma unroll
  for (int c = 0; c < Cc; ++c) out[m * Cc + c] = accv[c];
}

// ---------------------------------------------------------------------------
extern "C" void kernel_launch(void* const* d_in, const int* in_sizes, int n_in,
                              void* d_out, int out_size, void* d_ws, size_t ws_size,
                              hipStream_t stream) {
  const float* ctxt_vec = (const float*)d_in[1];   // [M][W][D]
  const float* cand_vec = (const float*)d_in[3];   // [M][C][D]
  const float* pem      = (const float*)d_in[4];   // [M][C]
  const float* A        = (const float*)d_in[5];
  const float* B        = (const float*)d_in[6];
  const float* Cl       = (const float*)d_in[7];
  const float* W1       = (const float*)d_in[8];
  const float* b1       = (const float*)d_in[9];
  const float* W2       = (const float*)d_in[10];
  const float* b2       = (const float*)d_in[11];
  float* out = (float*)d_out;

  char* ws = (char*)d_ws;
  _Float16* P     = (_Float16*)(ws);                      // 20,480,000 B
  _Float16* Ah    = (_Float16*)(ws + 20480000);           //  2,048,000 B
  _Float16* Bh    = (_Float16*)(ws + 20480000 + 2048000); //  2,048,000 B
  // emsg (fp16, 2,560,000 B) aliases Ah/Bh — both dead after the GEMM;
  // k_lbp (emsg writer) is stream-ordered after the GEMM.
  _Float16* emsg  = (_Float16*)(ws + 20480000);
  float*   scores = (float*)(ws + 25600000);              //     12,800 B
  float*   pp     = (float*)(ws + 25612800);              //    102,400 B [2][4][MC]

  k_entity<<<Mm, 512, 0, stream>>>(ctxt_vec, cand_vec, A, B, Cl, Ah, Bh, scores);

  k_pairwise_mfma<<<625, 256, 0, stream>>>(Ah, Bh, P);

  // ping-pong partials: it0->pp0, it1->pp1, ..., it4->pp0
  float* pp0 = pp;
  float* pp1 = pp + 4 * MC;
  for (int it = 0; it < LBP_ITERS; ++it) {
    float* pout = (it & 1) ? pp1 : pp0;
    float* pin  = (it & 1) ? pp0 : pp1;
    k_lbp<<<dim3(Mm, 4), 128, 0, stream>>>(
        P, scores, pin, pout, emsg, it == 0 ? 1 : 0);
  }
  // last iter (it=4) wrote pp0
  k_final2<<<(Mm + 63) / 64, 64, 0, stream>>>(
      scores, pp0, pem, W1, b1, W2, b2, out);
}